// Round 1
// baseline (1383.672 us; speedup 1.0000x reference)
//
#include <hip/hip_runtime.h>
#include <hip/hip_fp16.h>
#include <math.h>

#define NLEVELS 16
#define TPB 256
#define NXCD 8
#define MAXRUNS 8

struct Cfg {
    float    scale[NLEVELS];
    unsigned res[NLEVELS];
    unsigned offset[NLEVELS];    // entry offsets into table
    unsigned hash_mask;          // bit l => level l hashed (hmap = 2^19)
    // Per-XCD run schedule: XCD x executes, for seq = blockIdx>>3 in order,
    // contiguous runs of (level, chunk range). Dense runs first, then
    // hashed runs -- so each XCD's L2 holds at most ONE 2MB hashed table
    // at a time, and every XCD gets exactly 11/8 hashed-level-equivalents
    // (balanced regardless of dense:hashed cost ratio).
    int      run_level [NXCD][MAXRUNS];
    int      run_chunk0[NXCD][MAXRUNS];
    int      run_end   [NXCD][MAXRUNS]; // cumulative task count; sentinel INT_MAX
};

// ---- pre-pass: f32 table -> fp16 table in ws (halves gather working set) ----
__global__ __launch_bounds__(TPB) void convert_kernel(
    const float2* __restrict__ emb, __half2* __restrict__ tab, int n)
{
    int i = blockIdx.x * TPB + threadIdx.x;
    if (i < n) {
        float2 e = emb[i];
        tab[i] = __floats2half2_rn(e.x, e.y);
    }
}

// ---- level-partitioned gather. TO_WS: write ws[l][p] (coalesced), else out[p][l] ----
template <bool TO_WS>
__global__ __launch_bounds__(TPB) void gather_kernel(
    const float* __restrict__ in, const __half2* __restrict__ tab,
    float2* __restrict__ dst, Cfg cfg, int npts)
{
    const int xcd = blockIdx.x & (NXCD - 1);   // round-robin block->XCD
    const int seq = blockIdx.x >> 3;           // this XCD's task index

    // locate (level, chunk) for this task -- uniform scalar scan over <=8 runs
    int r = 0;
    while (seq >= cfg.run_end[xcd][r]) ++r;
    const int base  = (r == 0) ? 0 : cfg.run_end[xcd][r - 1];
    const int l     = cfg.run_level[xcd][r];
    const int chunk = cfg.run_chunk0[xcd][r] + (seq - base);

    const int p = chunk * TPB + threadIdx.x;
    if (p >= npts) return;

    const float x = in[3 * p + 0];
    const float y = in[3 * p + 1];
    const float z = in[3 * p + 2];

    const float    s   = cfg.scale[l];
    const unsigned rr  = cfg.res[l];
    const unsigned off = cfg.offset[l];
    const bool use_hash = (cfg.hash_mask >> l) & 1u;

    const float px = x * s + 0.5f;
    const float py = y * s + 0.5f;
    const float pz = z * s + 0.5f;
    const float fxf = floorf(px), fyf = floorf(py), fzf = floorf(pz);
    const float tx = px - fxf, ty = py - fyf, tz = pz - fzf;
    const unsigned gx = (unsigned)fxf, gy = (unsigned)fyf, gz = (unsigned)fzf;
    const unsigned rm1 = rr - 1u;

    float a0 = 0.0f, a1 = 0.0f;

    #pragma unroll
    for (int c = 0; c < 8; ++c) {
        const unsigned bx = c & 1u, by = (c >> 1) & 1u, bz = (c >> 2) & 1u;
        const unsigned cx = min(gx + bx, rm1);
        const unsigned cy = min(gy + by, rm1);
        const unsigned cz = min(gz + bz, rm1);
        const float w = (bx ? tx : 1.0f - tx)
                      * (by ? ty : 1.0f - ty)
                      * (bz ? tz : 1.0f - tz);
        unsigned idx;
        if (use_hash) {
            idx = (cx ^ (cy * 2654435761u) ^ (cz * 805459861u)) & 0x7FFFFu;
        } else {
            idx = cx + cy * rr + cz * rr * rr;
        }
        const float2 e = __half22float2(tab[off + idx]);
        a0 = fmaf(w, e.x, a0);
        a1 = fmaf(w, e.y, a1);
    }

    if (TO_WS) {
        dst[(size_t)l * npts + p] = make_float2(a0, a1);       // coalesced
    } else {
        dst[(size_t)p * NLEVELS + l] = make_float2(a0, a1);    // strided fallback
    }
}

// ---- ws[L][B] float2 -> out[B][L*2], full-128B-line stores per thread ----
__global__ __launch_bounds__(TPB) void transpose_kernel(
    const float2* __restrict__ ws, float4* __restrict__ out, int npts)
{
    int p = blockIdx.x * TPB + threadIdx.x;
    if (p >= npts) return;
    float2 v[NLEVELS];
    #pragma unroll
    for (int l = 0; l < NLEVELS; ++l) v[l] = ws[(size_t)l * npts + p];
    float4* o = out + (size_t)p * 8;
    #pragma unroll
    for (int i = 0; i < 8; ++i)
        o[i] = make_float4(v[2*i].x, v[2*i].y, v[2*i+1].x, v[2*i+1].y);
}

// ---- monolithic f32 fallback (round-1 kernel) if ws is too small ----
__global__ __launch_bounds__(TPB) void hashenc_mono_kernel(
    const float* __restrict__ in, const float* __restrict__ emb,
    float* __restrict__ out, Cfg cfg, int npts)
{
    int b = blockIdx.x * TPB + threadIdx.x;
    if (b >= npts) return;
    const float x = in[3*b], y = in[3*b+1], z = in[3*b+2];
    float2* o = reinterpret_cast<float2*>(out) + (size_t)NLEVELS * b;
    #pragma unroll 1
    for (int l = 0; l < NLEVELS; ++l) {
        const float s = cfg.scale[l];
        const unsigned r = cfg.res[l], off = cfg.offset[l];
        const bool use_hash = (cfg.hash_mask >> l) & 1u;
        const float px = x*s+0.5f, py = y*s+0.5f, pz = z*s+0.5f;
        const float fxf = floorf(px), fyf = floorf(py), fzf = floorf(pz);
        const float tx = px-fxf, ty = py-fyf, tz = pz-fzf;
        const unsigned gx = (unsigned)fxf, gy = (unsigned)fyf, gz = (unsigned)fzf;
        const unsigned rm1 = r - 1u;
        float a0 = 0.f, a1 = 0.f;
        #pragma unroll
        for (int c = 0; c < 8; ++c) {
            const unsigned bx = c&1u, by = (c>>1)&1u, bz = (c>>2)&1u;
            const unsigned cx = min(gx+bx, rm1), cy = min(gy+by, rm1), cz = min(gz+bz, rm1);
            const float w = (bx?tx:1.f-tx)*(by?ty:1.f-ty)*(bz?tz:1.f-tz);
            unsigned idx = use_hash ? ((cx ^ (cy*2654435761u) ^ (cz*805459861u)) & 0x7FFFFu)
                                    : (cx + cy*r + cz*r*r);
            const float2 e = *reinterpret_cast<const float2*>(emb + 2u*(off+idx));
            a0 = fmaf(w, e.x, a0); a1 = fmaf(w, e.y, a1);
        }
        o[l] = make_float2(a0, a1);
    }
}

extern "C" void kernel_launch(void* const* d_in, const int* in_sizes, int n_in,
                              void* d_out, int out_size, void* d_ws, size_t ws_size,
                              hipStream_t stream)
{
    const float* in  = (const float*)d_in[0];
    const float* emb = (const float*)d_in[1];
    float* out = (float*)d_out;
    const int npts = in_sizes[0] / 3;

    // Build level config exactly like the numpy reference (float64 math).
    Cfg cfg;
    const double pls_log2 = log2(2048.0 / 16.0) / 15.0;
    const long long max_params = 1ll << 19;
    long long off = 0;
    unsigned hash_mask = 0;
    for (int l = 0; l < NLEVELS; ++l) {
        const double scale = exp2((double)l * pls_log2) * 16.0 - 1.0;
        const int res = (int)ceil(scale) + 1;
        cfg.scale[l]  = (float)scale;
        cfg.res[l]    = (unsigned)res;
        cfg.offset[l] = (unsigned)off;
        long long params = (long long)res * res * res;
        if (params > max_params) { params = max_params; hash_mask |= (1u << l); }
        params = (params + 7) / 8 * 8;
        off += params;
    }
    cfg.hash_mask = hash_mask;
    const long long total_entries = off;  // 6098120

    const int chunks = (npts + TPB - 1) / TPB;

    // ---- per-XCD balanced run schedule ----
    // Tasks: 16 levels x `chunks` chunks = 16*chunks blocks; each XCD gets
    // exactly 2*chunks tasks (grid is a multiple of 8). Hashed tasks are
    // split evenly (11*chunks/8 per XCD, i.e. 1.375 levels), consumed in
    // contiguous per-level runs so at most one 2MB table is hot per L2 at
    // any time. Dense runs are placed first on every XCD.
    {
        int dense_lv[NLEVELS], hashed_lv[NLEVELS];
        int nd = 0, nh = 0;
        for (int l = 0; l < NLEVELS; ++l) {
            if ((hash_mask >> l) & 1u) hashed_lv[nh++] = l;
            else                       dense_lv[nd++]  = l;
        }
        for (int x = 0; x < NXCD; ++x)
            for (int r = 0; r < MAXRUNS; ++r) {
                cfg.run_level[x][r] = 0;
                cfg.run_chunk0[x][r] = 0;
                cfg.run_end[x][r] = 0x7fffffff;
            }
        const long long S = 2ll * chunks;                 // tasks per XCD
        const long long hq_total = (long long)nh * chunks;
        int di = 0, dc = 0, hi = 0, hc = 0;               // stream pointers
        for (int x = 0; x < NXCD; ++x) {
            long long hq = hq_total / NXCD + (x < (int)(hq_total % NXCD) ? 1 : 0);
            long long dq = S - hq;
            int nr = 0;
            long long acc = 0;
            while (dq > 0 && di < nd) {                   // dense runs first
                long long rem = (long long)chunks - dc;
                int take = (int)(rem < dq ? rem : dq);
                cfg.run_level [x][nr] = dense_lv[di];
                cfg.run_chunk0[x][nr] = dc;
                acc += take;
                cfg.run_end[x][nr] = (int)acc;
                dc += take; if (dc == chunks) { ++di; dc = 0; }
                dq -= take; ++nr;
            }
            while (hq > 0 && hi < nh) {                   // then hashed runs
                long long rem = (long long)chunks - hc;
                int take = (int)(rem < hq ? rem : hq);
                cfg.run_level [x][nr] = hashed_lv[hi];
                cfg.run_chunk0[x][nr] = hc;
                acc += take;
                cfg.run_end[x][nr] = (int)acc;
                hc += take; if (hc == chunks) { ++hi; hc = 0; }
                hq -= take; ++nr;
            }
            // remaining slots keep sentinel run_end = INT_MAX
        }
    }

    const size_t tab_bytes  = (size_t)total_entries * 4;           // half2/entry
    const size_t tab_pad    = (tab_bytes + 255) & ~(size_t)255;
    const size_t tr_bytes   = (size_t)NLEVELS * npts * 8;          // float2 staging

    if (ws_size >= tab_pad + tr_bytes) {
        __half2* tab = (__half2*)d_ws;
        float2*  wst = (float2*)((char*)d_ws + tab_pad);
        convert_kernel<<<(int)((total_entries + TPB - 1) / TPB), TPB, 0, stream>>>(
            (const float2*)emb, tab, (int)total_entries);
        gather_kernel<true><<<chunks * 16, TPB, 0, stream>>>(in, tab, wst, cfg, npts);
        transpose_kernel<<<chunks, TPB, 0, stream>>>(wst, (float4*)out, npts);
    } else if (ws_size >= tab_bytes) {
        __half2* tab = (__half2*)d_ws;
        convert_kernel<<<(int)((total_entries + TPB - 1) / TPB), TPB, 0, stream>>>(
            (const float2*)emb, tab, (int)total_entries);
        gather_kernel<false><<<chunks * 16, TPB, 0, stream>>>(in, tab, (float2*)out, cfg, npts);
    } else {
        hashenc_mono_kernel<<<chunks, TPB, 0, stream>>>(in, emb, out, cfg, npts);
    }
}

// Round 2
// 1158.536 us; speedup vs baseline: 1.1943x; 1.1943x over previous
//
#include <hip/hip_runtime.h>
#include <hip/hip_fp16.h>
#include <math.h>

#define NLEVELS 16
#define TPB 256
#define NXCD 8
#define MAXRUNS 8

struct Cfg {
    float    scale[NLEVELS];
    unsigned res[NLEVELS];
    unsigned offset[NLEVELS];    // entry offsets into table
    unsigned hash_mask;          // bit l => level l hashed (hmap = 2^19)
    // Per-XCD run schedule: XCD x executes, for seq = blockIdx>>3 in order,
    // contiguous runs of (level, chunk range). Dense runs first, then
    // hashed runs -- each XCD's L2 holds at most ONE 2MB hashed table at a
    // time, and every XCD gets exactly 11/8 hashed-level-equivalents.
    int      run_level [NXCD][MAXRUNS];
    int      run_chunk0[NXCD][MAXRUNS];
    int      run_end   [NXCD][MAXRUNS]; // cumulative task count; sentinel INT_MAX
};

// ---- pre-pass: f32 table -> fp16 table in ws (halves gather working set) ----
__global__ __launch_bounds__(TPB) void convert_kernel(
    const float2* __restrict__ emb, __half2* __restrict__ tab, int n)
{
    int i = blockIdx.x * TPB + threadIdx.x;
    if (i < n) {
        float2 e = emb[i];
        tab[i] = __floats2half2_rn(e.x, e.y);
    }
}

__device__ __forceinline__ float2 h2u_to_f2(unsigned u)
{
    union { unsigned u; __half2 h; } cv;
    cv.u = u;
    return __half22float2(cv.h);
}

// ---- level-partitioned gather with paired-8B corner loads.
// x-corner pair {gx, gx+1}: for hashed levels with gx even this is the
// aligned entry pair {h, h^1} (hash x-prime is 1); for dense levels it is
// {idx, idx+1}, pair-resident iff idx even. One uint2 load serves both
// corners; otherwise one extra predicated 4B load. Cuts L2 request count
// ~8 -> ~6 per point (the gather is request-rate bound, not byte bound).
// TO_WS: write ws[l][p] as half2 (coalesced, 4B); else float2 out[p][l].
template <bool TO_WS>
__global__ __launch_bounds__(TPB) void gather_kernel(
    const float* __restrict__ in, const __half2* __restrict__ tab,
    void* __restrict__ dst, Cfg cfg, int npts)
{
    const int xcd = blockIdx.x & (NXCD - 1);   // round-robin block->XCD
    const int seq = blockIdx.x >> 3;           // this XCD's task index

    int r = 0;
    while (seq >= cfg.run_end[xcd][r]) ++r;
    const int base  = (r == 0) ? 0 : cfg.run_end[xcd][r - 1];
    const int l     = cfg.run_level[xcd][r];
    const int chunk = cfg.run_chunk0[xcd][r] + (seq - base);

    const int p = chunk * TPB + threadIdx.x;
    if (p >= npts) return;

    const float x = in[3 * p + 0];
    const float y = in[3 * p + 1];
    const float z = in[3 * p + 2];

    const float    s   = cfg.scale[l];
    const unsigned rr  = cfg.res[l];
    const unsigned off = cfg.offset[l];
    const bool use_hash = (cfg.hash_mask >> l) & 1u;

    const float px = x * s + 0.5f;
    const float py = y * s + 0.5f;
    const float pz = z * s + 0.5f;
    const float fxf = floorf(px), fyf = floorf(py), fzf = floorf(pz);
    const float tx = px - fxf, ty = py - fyf, tz = pz - fzf;
    const unsigned gx = (unsigned)fxf, gy = (unsigned)fyf, gz = (unsigned)fzf;
    const unsigned rm1 = rr - 1u;
    const unsigned cx1 = min(gx + 1u, rm1);
    const unsigned cy1 = min(gy + 1u, rm1);
    const unsigned cz1 = min(gz + 1u, rm1);

    // 4 (y,z)-corner terms
    unsigned t0, t1, t2, t3;
    if (use_hash) {
        const unsigned hy0 = gy  * 2654435761u, hy1 = cy1 * 2654435761u;
        const unsigned hz0 = gz  * 805459861u,  hz1 = cz1 * 805459861u;
        t0 = hy0 ^ hz0; t1 = hy1 ^ hz0; t2 = hy0 ^ hz1; t3 = hy1 ^ hz1;
    } else {
        const unsigned r2 = rr * rr;
        t0 = gy * rr + gz * r2;  t1 = cy1 * rr + gz * r2;
        t2 = gy * rr + cz1 * r2; t3 = cy1 * rr + cz1 * r2;
    }
    unsigned t[4] = {t0, t1, t2, t3};

    unsigned h0[4], h1[4];
    #pragma unroll
    for (int j = 0; j < 4; ++j) {
        if (use_hash) {
            h0[j] = (gx  ^ t[j]) & 0x7FFFFu;
            h1[j] = (cx1 ^ t[j]) & 0x7FFFFu;
        } else {
            h0[j] = gx  + t[j];
            h1[j] = cx1 + t[j];
        }
    }

    // batch A: 4 unconditional aligned 8B pair loads (cover x0 always,
    // and x1 too when it lands in the same pair)
    uint2 pr[4];
    #pragma unroll
    for (int j = 0; j < 4; ++j)
        pr[j] = *reinterpret_cast<const uint2*>(tab + off + (h0[j] & ~1u));

    // batch B: predicated 4B loads for x1 corners outside the pair
    unsigned e1w[4];
    #pragma unroll
    for (int j = 0; j < 4; ++j) {
        if ((h1[j] & ~1u) == (h0[j] & ~1u)) {
            e1w[j] = (h1[j] & 1u) ? pr[j].y : pr[j].x;
        } else {
            e1w[j] = *reinterpret_cast<const unsigned*>(tab + off + h1[j]);
        }
    }

    const float wx0 = 1.0f - tx, wx1 = tx;
    const float wy0 = 1.0f - ty, wy1 = ty;
    const float wz0 = 1.0f - tz, wz1 = tz;
    const float wyz[4] = {wy0 * wz0, wy1 * wz0, wy0 * wz1, wy1 * wz1};

    float a0 = 0.0f, a1 = 0.0f;
    #pragma unroll
    for (int j = 0; j < 4; ++j) {
        const float2 e0 = h2u_to_f2((h0[j] & 1u) ? pr[j].y : pr[j].x);
        const float2 e1 = h2u_to_f2(e1w[j]);
        const float w0 = wyz[j] * wx0, w1 = wyz[j] * wx1;
        a0 = fmaf(w0, e0.x, fmaf(w1, e1.x, a0));
        a1 = fmaf(w0, e0.y, fmaf(w1, e1.y, a1));
    }

    if (TO_WS) {
        ((__half2*)dst)[(size_t)l * npts + p] = __floats2half2_rn(a0, a1);
    } else {
        ((float2*)dst)[(size_t)p * NLEVELS + l] = make_float2(a0, a1);
    }
}

// ---- ws[L][B] half2 -> out[B][L*2] f32, full-128B-line stores per thread ----
__global__ __launch_bounds__(TPB) void transpose_kernel(
    const __half2* __restrict__ ws, float4* __restrict__ out, int npts)
{
    int p = blockIdx.x * TPB + threadIdx.x;
    if (p >= npts) return;
    __half2 v[NLEVELS];
    #pragma unroll
    for (int l = 0; l < NLEVELS; ++l) v[l] = ws[(size_t)l * npts + p];
    float4* o = out + (size_t)p * 8;
    #pragma unroll
    for (int i = 0; i < 8; ++i) {
        const float2 a = __half22float2(v[2 * i]);
        const float2 b = __half22float2(v[2 * i + 1]);
        o[i] = make_float4(a.x, a.y, b.x, b.y);
    }
}

// ---- monolithic f32 fallback (round-1 kernel) if ws is too small ----
__global__ __launch_bounds__(TPB) void hashenc_mono_kernel(
    const float* __restrict__ in, const float* __restrict__ emb,
    float* __restrict__ out, Cfg cfg, int npts)
{
    int b = blockIdx.x * TPB + threadIdx.x;
    if (b >= npts) return;
    const float x = in[3*b], y = in[3*b+1], z = in[3*b+2];
    float2* o = reinterpret_cast<float2*>(out) + (size_t)NLEVELS * b;
    #pragma unroll 1
    for (int l = 0; l < NLEVELS; ++l) {
        const float s = cfg.scale[l];
        const unsigned r = cfg.res[l], off = cfg.offset[l];
        const bool use_hash = (cfg.hash_mask >> l) & 1u;
        const float px = x*s+0.5f, py = y*s+0.5f, pz = z*s+0.5f;
        const float fxf = floorf(px), fyf = floorf(py), fzf = floorf(pz);
        const float tx = px-fxf, ty = py-fyf, tz = pz-fzf;
        const unsigned gx = (unsigned)fxf, gy = (unsigned)fyf, gz = (unsigned)fzf;
        const unsigned rm1 = r - 1u;
        float a0 = 0.f, a1 = 0.f;
        #pragma unroll
        for (int c = 0; c < 8; ++c) {
            const unsigned bx = c&1u, by = (c>>1)&1u, bz = (c>>2)&1u;
            const unsigned cx = min(gx+bx, rm1), cy = min(gy+by, rm1), cz = min(gz+bz, rm1);
            const float w = (bx?tx:1.f-tx)*(by?ty:1.f-ty)*(bz?tz:1.f-tz);
            unsigned idx = use_hash ? ((cx ^ (cy*2654435761u) ^ (cz*805459861u)) & 0x7FFFFu)
                                    : (cx + cy*r + cz*r*r);
            const float2 e = *reinterpret_cast<const float2*>(emb + 2u*(off+idx));
            a0 = fmaf(w, e.x, a0); a1 = fmaf(w, e.y, a1);
        }
        o[l] = make_float2(a0, a1);
    }
}

extern "C" void kernel_launch(void* const* d_in, const int* in_sizes, int n_in,
                              void* d_out, int out_size, void* d_ws, size_t ws_size,
                              hipStream_t stream)
{
    const float* in  = (const float*)d_in[0];
    const float* emb = (const float*)d_in[1];
    float* out = (float*)d_out;
    const int npts = in_sizes[0] / 3;

    // Build level config exactly like the numpy reference (float64 math).
    Cfg cfg;
    const double pls_log2 = log2(2048.0 / 16.0) / 15.0;
    const long long max_params = 1ll << 19;
    long long off = 0;
    unsigned hash_mask = 0;
    for (int l = 0; l < NLEVELS; ++l) {
        const double scale = exp2((double)l * pls_log2) * 16.0 - 1.0;
        const int res = (int)ceil(scale) + 1;
        cfg.scale[l]  = (float)scale;
        cfg.res[l]    = (unsigned)res;
        cfg.offset[l] = (unsigned)off;
        long long params = (long long)res * res * res;
        if (params > max_params) { params = max_params; hash_mask |= (1u << l); }
        params = (params + 7) / 8 * 8;
        off += params;
    }
    cfg.hash_mask = hash_mask;
    const long long total_entries = off;  // 6098120

    const int chunks = (npts + TPB - 1) / TPB;

    // ---- per-XCD balanced run schedule (see Cfg comment) ----
    {
        int dense_lv[NLEVELS], hashed_lv[NLEVELS];
        int nd = 0, nh = 0;
        for (int l = 0; l < NLEVELS; ++l) {
            if ((hash_mask >> l) & 1u) hashed_lv[nh++] = l;
            else                       dense_lv[nd++]  = l;
        }
        for (int x = 0; x < NXCD; ++x)
            for (int r = 0; r < MAXRUNS; ++r) {
                cfg.run_level[x][r] = 0;
                cfg.run_chunk0[x][r] = 0;
                cfg.run_end[x][r] = 0x7fffffff;
            }
        const long long S = 2ll * chunks;                 // tasks per XCD
        const long long hq_total = (long long)nh * chunks;
        int di = 0, dc = 0, hi = 0, hc = 0;               // stream pointers
        for (int x = 0; x < NXCD; ++x) {
            long long hq = hq_total / NXCD + (x < (int)(hq_total % NXCD) ? 1 : 0);
            long long dq = S - hq;
            int nr = 0;
            long long acc = 0;
            while (dq > 0 && di < nd) {                   // dense runs first
                long long rem = (long long)chunks - dc;
                int take = (int)(rem < dq ? rem : dq);
                cfg.run_level [x][nr] = dense_lv[di];
                cfg.run_chunk0[x][nr] = dc;
                acc += take;
                cfg.run_end[x][nr] = (int)acc;
                dc += take; if (dc == chunks) { ++di; dc = 0; }
                dq -= take; ++nr;
            }
            while (hq > 0 && hi < nh) {                   // then hashed runs
                long long rem = (long long)chunks - hc;
                int take = (int)(rem < hq ? rem : hq);
                cfg.run_level [x][nr] = hashed_lv[hi];
                cfg.run_chunk0[x][nr] = hc;
                acc += take;
                cfg.run_end[x][nr] = (int)acc;
                hc += take; if (hc == chunks) { ++hi; hc = 0; }
                hq -= take; ++nr;
            }
        }
    }

    const size_t tab_bytes  = (size_t)total_entries * 4;           // half2/entry
    const size_t tab_pad    = (tab_bytes + 255) & ~(size_t)255;
    const size_t tr_bytes   = (size_t)NLEVELS * npts * 4;          // half2 staging

    if (ws_size >= tab_pad + tr_bytes) {
        __half2* tab = (__half2*)d_ws;
        __half2* wst = (__half2*)((char*)d_ws + tab_pad);
        convert_kernel<<<(int)((total_entries + TPB - 1) / TPB), TPB, 0, stream>>>(
            (const float2*)emb, tab, (int)total_entries);
        gather_kernel<true><<<chunks * 16, TPB, 0, stream>>>(in, tab, wst, cfg, npts);
        transpose_kernel<<<chunks, TPB, 0, stream>>>(wst, (float4*)out, npts);
    } else if (ws_size >= tab_bytes) {
        __half2* tab = (__half2*)d_ws;
        convert_kernel<<<(int)((total_entries + TPB - 1) / TPB), TPB, 0, stream>>>(
            (const float2*)emb, tab, (int)total_entries);
        gather_kernel<false><<<chunks * 16, TPB, 0, stream>>>(in, tab, (float2*)out, cfg, npts);
    } else {
        hashenc_mono_kernel<<<chunks, TPB, 0, stream>>>(in, emb, out, cfg, npts);
    }
}

// Round 4
// 1152.056 us; speedup vs baseline: 1.2010x; 1.0056x over previous
//
#include <hip/hip_runtime.h>
#include <hip/hip_fp16.h>
#include <math.h>

#define NLEVELS 16
#define TPB 256
#define NXCD 8
#define MAXRUNS 8

struct Cfg {
    float    scale[NLEVELS];
    unsigned res[NLEVELS];
    unsigned offset[NLEVELS];    // entry offsets into table
    unsigned hash_mask;          // bit l => level l hashed (hmap = 2^19)
    // Per-XCD run schedule: XCD x executes, for seq = blockIdx>>3 in order,
    // contiguous runs of (level, chunk range). Dense runs first, then
    // hashed runs -- each XCD's L2 holds at most ONE 2MB hashed table at a
    // time, and every XCD gets exactly 11/8 hashed-level-equivalents.
    int      run_level [NXCD][MAXRUNS];
    int      run_chunk0[NXCD][MAXRUNS];
    int      run_end   [NXCD][MAXRUNS]; // cumulative task count; sentinel INT_MAX
};

// ---- pre-pass: f32 table -> fp16 table in ws (halves gather working set) ----
__global__ __launch_bounds__(TPB) void convert_kernel(
    const float2* __restrict__ emb, __half2* __restrict__ tab, int n)
{
    int i = blockIdx.x * TPB + threadIdx.x;
    if (i < n) {
        float2 e = emb[i];
        tab[i] = __floats2half2_rn(e.x, e.y);
    }
}

__device__ __forceinline__ float2 h2u_to_f2(unsigned u)
{
    union { unsigned u; __half2 h; } cv;
    cv.u = u;
    return __half22float2(cv.h);
}

// ---- level-partitioned gather with paired-8B corner loads.
// x-corner pair {gx, gx+1}: hashed levels use x-prime 1, so with gx even the
// pair is the aligned entry pair {h, h^1}; dense levels give {idx, idx+1},
// pair-resident iff idx even. One uint2 load serves both corners, else one
// extra predicated 4B load: ~8 -> ~6 L2 requests per point.
// ALL per-corner state is in named scalars -- NO private arrays (round-2's
// arrays were demoted to LDS by PromoteAlloca: 8KB/block + 43M bank-conflict
// cycles, cancelling the request-reduction win).
// TO_WS: write ws[l][p] as half2 (coalesced, 4B); else float2 out[p][l].
template <bool TO_WS>
__global__ __launch_bounds__(TPB) void gather_kernel(
    const float* __restrict__ in, const __half2* __restrict__ tab,
    void* __restrict__ dst, Cfg cfg, int npts)
{
    const int xcd = blockIdx.x & (NXCD - 1);   // round-robin block->XCD
    const int seq = blockIdx.x >> 3;           // this XCD's task index

    int r = 0;
    while (seq >= cfg.run_end[xcd][r]) ++r;
    const int base  = (r == 0) ? 0 : cfg.run_end[xcd][r - 1];
    const int l     = cfg.run_level[xcd][r];
    const int chunk = cfg.run_chunk0[xcd][r] + (seq - base);

    const int p = chunk * TPB + threadIdx.x;
    if (p >= npts) return;

    const float x = in[3 * p + 0];
    const float y = in[3 * p + 1];
    const float z = in[3 * p + 2];

    const float    s   = cfg.scale[l];
    const unsigned rr  = cfg.res[l];
    const unsigned off = cfg.offset[l];
    const bool use_hash = (cfg.hash_mask >> l) & 1u;

    const float px = x * s + 0.5f;
    const float py = y * s + 0.5f;
    const float pz = z * s + 0.5f;
    const float fxf = floorf(px), fyf = floorf(py), fzf = floorf(pz);
    const float tx = px - fxf, ty = py - fyf, tz = pz - fzf;
    const unsigned gx = (unsigned)fxf, gy = (unsigned)fyf, gz = (unsigned)fzf;
    const unsigned rm1 = rr - 1u;
    const unsigned cx1 = min(gx + 1u, rm1);
    const unsigned cy1 = min(gy + 1u, rm1);
    const unsigned cz1 = min(gz + 1u, rm1);

    // 4 (y,z)-corner terms + per-corner base/neighbor indices, all scalar
    unsigned h0a, h0b, h0c, h0d, h1a, h1b, h1c, h1d;
    if (use_hash) {
        const unsigned hy0 = gy  * 2654435761u, hy1 = cy1 * 2654435761u;
        const unsigned hz0 = gz  * 805459861u,  hz1 = cz1 * 805459861u;
        const unsigned ta = hy0 ^ hz0, tb = hy1 ^ hz0;
        const unsigned tc = hy0 ^ hz1, td = hy1 ^ hz1;
        h0a = (gx ^ ta) & 0x7FFFFu;  h1a = (cx1 ^ ta) & 0x7FFFFu;
        h0b = (gx ^ tb) & 0x7FFFFu;  h1b = (cx1 ^ tb) & 0x7FFFFu;
        h0c = (gx ^ tc) & 0x7FFFFu;  h1c = (cx1 ^ tc) & 0x7FFFFu;
        h0d = (gx ^ td) & 0x7FFFFu;  h1d = (cx1 ^ td) & 0x7FFFFu;
    } else {
        const unsigned r2 = rr * rr;
        const unsigned ta = gy * rr + gz * r2,  tb = cy1 * rr + gz * r2;
        const unsigned tc = gy * rr + cz1 * r2, td = cy1 * rr + cz1 * r2;
        h0a = gx + ta;  h1a = cx1 + ta;
        h0b = gx + tb;  h1b = cx1 + tb;
        h0c = gx + tc;  h1c = cx1 + tc;
        h0d = gx + td;  h1d = cx1 + td;
    }

    const __half2* tbl = tab + off;

    // batch A: 4 unconditional aligned 8B pair loads
    const uint2 pa = *reinterpret_cast<const uint2*>(tbl + (h0a & ~1u));
    const uint2 pb = *reinterpret_cast<const uint2*>(tbl + (h0b & ~1u));
    const uint2 pc = *reinterpret_cast<const uint2*>(tbl + (h0c & ~1u));
    const uint2 pd = *reinterpret_cast<const uint2*>(tbl + (h0d & ~1u));

    // batch B: predicated 4B loads for x1 corners outside the pair
    unsigned ea, eb, ec, ed;
    if ((h1a >> 1) == (h0a >> 1)) ea = (h1a & 1u) ? pa.y : pa.x;
    else                          ea = *reinterpret_cast<const unsigned*>(tbl + h1a);
    if ((h1b >> 1) == (h0b >> 1)) eb = (h1b & 1u) ? pb.y : pb.x;
    else                          eb = *reinterpret_cast<const unsigned*>(tbl + h1b);
    if ((h1c >> 1) == (h0c >> 1)) ec = (h1c & 1u) ? pc.y : pc.x;
    else                          ec = *reinterpret_cast<const unsigned*>(tbl + h1c);
    if ((h1d >> 1) == (h0d >> 1)) ed = (h1d & 1u) ? pd.y : pd.x;
    else                          ed = *reinterpret_cast<const unsigned*>(tbl + h1d);

    const float wx0 = 1.0f - tx, wx1 = tx;
    const float wy0 = 1.0f - ty, wy1 = ty;
    const float wz0 = 1.0f - tz, wz1 = tz;
    const float wa = wy0 * wz0, wb = wy1 * wz0, wc = wy0 * wz1, wd = wy1 * wz1;

    float a0 = 0.0f, a1 = 0.0f;
    {
        const float2 e0 = h2u_to_f2((h0a & 1u) ? pa.y : pa.x);
        const float2 e1 = h2u_to_f2(ea);
        a0 = fmaf(wa * wx0, e0.x, fmaf(wa * wx1, e1.x, a0));
        a1 = fmaf(wa * wx0, e0.y, fmaf(wa * wx1, e1.y, a1));
    }
    {
        const float2 e0 = h2u_to_f2((h0b & 1u) ? pb.y : pb.x);
        const float2 e1 = h2u_to_f2(eb);
        a0 = fmaf(wb * wx0, e0.x, fmaf(wb * wx1, e1.x, a0));
        a1 = fmaf(wb * wx0, e0.y, fmaf(wb * wx1, e1.y, a1));
    }
    {
        const float2 e0 = h2u_to_f2((h0c & 1u) ? pc.y : pc.x);
        const float2 e1 = h2u_to_f2(ec);
        a0 = fmaf(wc * wx0, e0.x, fmaf(wc * wx1, e1.x, a0));
        a1 = fmaf(wc * wx0, e0.y, fmaf(wc * wx1, e1.y, a1));
    }
    {
        const float2 e0 = h2u_to_f2((h0d & 1u) ? pd.y : pd.x);
        const float2 e1 = h2u_to_f2(ed);
        a0 = fmaf(wd * wx0, e0.x, fmaf(wd * wx1, e1.x, a0));
        a1 = fmaf(wd * wx0, e0.y, fmaf(wd * wx1, e1.y, a1));
    }

    if (TO_WS) {
        ((__half2*)dst)[(size_t)l * npts + p] = __floats2half2_rn(a0, a1);
    } else {
        ((float2*)dst)[(size_t)p * NLEVELS + l] = make_float2(a0, a1);
    }
}

// ---- ws[L][B] half2 -> out[B][L*2] f32, full-128B-line stores per thread ----
__global__ __launch_bounds__(TPB) void transpose_kernel(
    const __half2* __restrict__ ws, float4* __restrict__ out, int npts)
{
    int p = blockIdx.x * TPB + threadIdx.x;
    if (p >= npts) return;
    __half2 v0  = ws[(size_t) 0 * npts + p], v1  = ws[(size_t) 1 * npts + p];
    __half2 v2  = ws[(size_t) 2 * npts + p], v3  = ws[(size_t) 3 * npts + p];
    __half2 v4  = ws[(size_t) 4 * npts + p], v5  = ws[(size_t) 5 * npts + p];
    __half2 v6  = ws[(size_t) 6 * npts + p], v7  = ws[(size_t) 7 * npts + p];
    __half2 v8  = ws[(size_t) 8 * npts + p], v9  = ws[(size_t) 9 * npts + p];
    __half2 v10 = ws[(size_t)10 * npts + p], v11 = ws[(size_t)11 * npts + p];
    __half2 v12 = ws[(size_t)12 * npts + p], v13 = ws[(size_t)13 * npts + p];
    __half2 v14 = ws[(size_t)14 * npts + p], v15 = ws[(size_t)15 * npts + p];
    float4* o = out + (size_t)p * 8;
    #define OUT2(i, va, vb) { const float2 fa = __half22float2(va); \
        const float2 fb = __half22float2(vb); \
        o[i] = make_float4(fa.x, fa.y, fb.x, fb.y); }
    OUT2(0, v0,  v1)  OUT2(1, v2,  v3)  OUT2(2, v4,  v5)  OUT2(3, v6,  v7)
    OUT2(4, v8,  v9)  OUT2(5, v10, v11) OUT2(6, v12, v13) OUT2(7, v14, v15)
    #undef OUT2
}

// ---- monolithic f32 fallback (round-1 kernel) if ws is too small ----
__global__ __launch_bounds__(TPB) void hashenc_mono_kernel(
    const float* __restrict__ in, const float* __restrict__ emb,
    float* __restrict__ out, Cfg cfg, int npts)
{
    int b = blockIdx.x * TPB + threadIdx.x;
    if (b >= npts) return;
    const float x = in[3*b], y = in[3*b+1], z = in[3*b+2];
    float2* o = reinterpret_cast<float2*>(out) + (size_t)NLEVELS * b;
    #pragma unroll 1
    for (int l = 0; l < NLEVELS; ++l) {
        const float s = cfg.scale[l];
        const unsigned r = cfg.res[l], off = cfg.offset[l];
        const bool use_hash = (cfg.hash_mask >> l) & 1u;
        const float px = x*s+0.5f, py = y*s+0.5f, pz = z*s+0.5f;
        const float fxf = floorf(px), fyf = floorf(py), fzf = floorf(pz);
        const float tx = px-fxf, ty = py-fyf, tz = pz-fzf;
        const unsigned gx = (unsigned)fxf, gy = (unsigned)fyf, gz = (unsigned)fzf;
        const unsigned rm1 = r - 1u;
        float a0 = 0.f, a1 = 0.f;
        #pragma unroll
        for (int c = 0; c < 8; ++c) {
            const unsigned bx = c&1u, by = (c>>1)&1u, bz = (c>>2)&1u;
            const unsigned cx = min(gx+bx, rm1), cy = min(gy+by, rm1), cz = min(gz+bz, rm1);
            const float w = (bx?tx:1.f-tx)*(by?ty:1.f-ty)*(bz?tz:1.f-tz);
            unsigned idx = use_hash ? ((cx ^ (cy*2654435761u) ^ (cz*805459861u)) & 0x7FFFFu)
                                    : (cx + cy*r + cz*r*r);
            const float2 e = *reinterpret_cast<const float2*>(emb + 2u*(off+idx));
            a0 = fmaf(w, e.x, a0); a1 = fmaf(w, e.y, a1);
        }
        o[l] = make_float2(a0, a1);
    }
}

extern "C" void kernel_launch(void* const* d_in, const int* in_sizes, int n_in,
                              void* d_out, int out_size, void* d_ws, size_t ws_size,
                              hipStream_t stream)
{
    const float* in  = (const float*)d_in[0];
    const float* emb = (const float*)d_in[1];
    float* out = (float*)d_out;
    const int npts = in_sizes[0] / 3;

    // Build level config exactly like the numpy reference (float64 math).
    Cfg cfg;
    const double pls_log2 = log2(2048.0 / 16.0) / 15.0;
    const long long max_params = 1ll << 19;
    long long off = 0;
    unsigned hash_mask = 0;
    for (int l = 0; l < NLEVELS; ++l) {
        const double scale = exp2((double)l * pls_log2) * 16.0 - 1.0;
        const int res = (int)ceil(scale) + 1;
        cfg.scale[l]  = (float)scale;
        cfg.res[l]    = (unsigned)res;
        cfg.offset[l] = (unsigned)off;
        long long params = (long long)res * res * res;
        if (params > max_params) { params = max_params; hash_mask |= (1u << l); }
        params = (params + 7) / 8 * 8;
        off += params;
    }
    cfg.hash_mask = hash_mask;
    const long long total_entries = off;  // 6098120

    const int chunks = (npts + TPB - 1) / TPB;

    // ---- per-XCD balanced run schedule (see Cfg comment) ----
    {
        int dense_lv[NLEVELS], hashed_lv[NLEVELS];
        int nd = 0, nh = 0;
        for (int l = 0; l < NLEVELS; ++l) {
            if ((hash_mask >> l) & 1u) hashed_lv[nh++] = l;
            else                       dense_lv[nd++]  = l;
        }
        for (int x = 0; x < NXCD; ++x)
            for (int r = 0; r < MAXRUNS; ++r) {
                cfg.run_level[x][r] = 0;
                cfg.run_chunk0[x][r] = 0;
                cfg.run_end[x][r] = 0x7fffffff;
            }
        const long long S = 2ll * chunks;                 // tasks per XCD
        const long long hq_total = (long long)nh * chunks;
        int di = 0, dc = 0, hi = 0, hc = 0;               // stream pointers
        for (int x = 0; x < NXCD; ++x) {
            long long hq = hq_total / NXCD + (x < (int)(hq_total % NXCD) ? 1 : 0);
            long long dq = S - hq;
            int nr = 0;
            long long acc = 0;
            while (dq > 0 && di < nd) {                   // dense runs first
                long long rem = (long long)chunks - dc;
                int take = (int)(rem < dq ? rem : dq);
                cfg.run_level [x][nr] = dense_lv[di];
                cfg.run_chunk0[x][nr] = dc;
                acc += take;
                cfg.run_end[x][nr] = (int)acc;
                dc += take; if (dc == chunks) { ++di; dc = 0; }
                dq -= take; ++nr;
            }
            while (hq > 0 && hi < nh) {                   // then hashed runs
                long long rem = (long long)chunks - hc;
                int take = (int)(rem < hq ? rem : hq);
                cfg.run_level [x][nr] = hashed_lv[hi];
                cfg.run_chunk0[x][nr] = hc;
                acc += take;
                cfg.run_end[x][nr] = (int)acc;
                hc += take; if (hc == chunks) { ++hi; hc = 0; }
                hq -= take; ++nr;
            }
        }
    }

    const size_t tab_bytes  = (size_t)total_entries * 4;           // half2/entry
    const size_t tab_pad    = (tab_bytes + 255) & ~(size_t)255;
    const size_t tr_bytes   = (size_t)NLEVELS * npts * 4;          // half2 staging

    if (ws_size >= tab_pad + tr_bytes) {
        __half2* tab = (__half2*)d_ws;
        __half2* wst = (__half2*)((char*)d_ws + tab_pad);
        convert_kernel<<<(int)((total_entries + TPB - 1) / TPB), TPB, 0, stream>>>(
            (const float2*)emb, tab, (int)total_entries);
        gather_kernel<true><<<chunks * 16, TPB, 0, stream>>>(in, tab, wst, cfg, npts);
        transpose_kernel<<<chunks, TPB, 0, stream>>>(wst, (float4*)out, npts);
    } else if (ws_size >= tab_bytes) {
        __half2* tab = (__half2*)d_ws;
        convert_kernel<<<(int)((total_entries + TPB - 1) / TPB), TPB, 0, stream>>>(
            (const float2*)emb, tab, (int)total_entries);
        gather_kernel<false><<<chunks * 16, TPB, 0, stream>>>(in, tab, (float2*)out, cfg, npts);
    } else {
        hashenc_mono_kernel<<<chunks, TPB, 0, stream>>>(in, emb, out, cfg, npts);
    }
}

// Round 6
// 1062.752 us; speedup vs baseline: 1.3020x; 1.0840x over previous
//
#include <hip/hip_runtime.h>
#include <hip/hip_fp16.h>
#include <math.h>

#define NLEVELS 16
#define TPB 256
#define NXCD 8
#define MAXRUNS 8

struct Cfg {
    float    scale[NLEVELS];
    unsigned res[NLEVELS];
    unsigned offset[NLEVELS];    // entry offsets into table
    int      ws_row[NLEVELS];    // >=0: row in ws staging (hashed), -1: dense
    // Per-XCD run schedule over HASHED levels only: XCD x executes, for
    // seq = blockIdx>>3 in order, contiguous runs of (level, chunk range),
    // so each XCD's L2 holds ~one 2MB hashed table at a time and every XCD
    // gets 11/8 hashed-level-equivalents of work.
    int      run_level [NXCD][MAXRUNS];
    int      run_chunk0[NXCD][MAXRUNS];
    int      run_end   [NXCD][MAXRUNS]; // cumulative task count; sentinel INT_MAX
    int      n_tasks   [NXCD];          // real task count per XCD
};

// ---- pre-pass: f32 table -> fp16 table in ws (halves gather working set) ----
__global__ __launch_bounds__(TPB) void convert_kernel(
    const float2* __restrict__ emb, __half2* __restrict__ tab, int n)
{
    int i = blockIdx.x * TPB + threadIdx.x;
    if (i < n) {
        float2 e = emb[i];
        tab[i] = __floats2half2_rn(e.x, e.y);
    }
}

__device__ __forceinline__ float2 h2u_to_f2(unsigned u)
{
    union { unsigned u; __half2 h; } cv;
    cv.u = u;
    return __half22float2(cv.h);
}

// ---- agent-scope (sc0) loads: L1-bypass for the random hashed-table gather.
// gfx950 memory model: agent-scope relaxed load lowers to global_load ... sc0
// (L1 is per-CU non-coherent, so agent-scope reads come from L2). L1 hit rate
// on a 2MB random-accessed table is <2%, so skipping L1 allocation removes
// pure overhead from the TCP miss path. Portable HIP spelling (round-5's raw
// buffer builtins changed signature in ROCm 7 -> compile failure).
__device__ __forceinline__ unsigned long long ld_agent_u64(const void* p)
{
    return __hip_atomic_load((const unsigned long long*)p,
                             __ATOMIC_RELAXED, __HIP_MEMORY_SCOPE_AGENT);
}
__device__ __forceinline__ unsigned ld_agent_u32(const void* p)
{
    return __hip_atomic_load((const unsigned*)p,
                             __ATOMIC_RELAXED, __HIP_MEMORY_SCOPE_AGENT);
}

// ---- hashed-level gather with paired-8B corner loads + sc0.
// x-corner pair {gx, gx+1}: hash x-prime is 1, so with gx even the pair is
// the aligned entry pair {h, h^1}. One 8B load serves both corners, else one
// extra predicated 4B load. All state in named scalars (NO private arrays --
// PromoteAlloca demotes them to LDS: round-2 lesson).
// Writes ws[row][p] as half2 (coalesced).
__global__ __launch_bounds__(TPB) void gather_kernel(
    const float* __restrict__ in, const __half2* __restrict__ tab,
    __half2* __restrict__ ws, Cfg cfg, int npts)
{
    const int xcd = blockIdx.x & (NXCD - 1);   // round-robin block->XCD
    const int seq = blockIdx.x >> 3;           // this XCD's task index
    if (seq >= cfg.n_tasks[xcd]) return;

    int r = 0;
    while (seq >= cfg.run_end[xcd][r]) ++r;
    const int base  = (r == 0) ? 0 : cfg.run_end[xcd][r - 1];
    const int l     = cfg.run_level[xcd][r];
    const int chunk = cfg.run_chunk0[xcd][r] + (seq - base);

    const int p = chunk * TPB + threadIdx.x;
    if (p >= npts) return;

    const float x = in[3 * p + 0];
    const float y = in[3 * p + 1];
    const float z = in[3 * p + 2];

    const float    s    = cfg.scale[l];
    const unsigned rr   = cfg.res[l];
    const unsigned offw = cfg.offset[l];

    const float px = x * s + 0.5f;
    const float py = y * s + 0.5f;
    const float pz = z * s + 0.5f;
    const float fxf = floorf(px), fyf = floorf(py), fzf = floorf(pz);
    const float tx = px - fxf, ty = py - fyf, tz = pz - fzf;
    const unsigned gx = (unsigned)fxf, gy = (unsigned)fyf, gz = (unsigned)fzf;
    const unsigned rm1 = rr - 1u;
    const unsigned cx1 = min(gx + 1u, rm1);
    const unsigned cy1 = min(gy + 1u, rm1);
    const unsigned cz1 = min(gz + 1u, rm1);

    // 4 (y,z)-corner hash terms + per-corner base/neighbor indices, all scalar
    const unsigned hy0 = gy  * 2654435761u, hy1 = cy1 * 2654435761u;
    const unsigned hz0 = gz  * 805459861u,  hz1 = cz1 * 805459861u;
    const unsigned ta = hy0 ^ hz0, tb = hy1 ^ hz0;
    const unsigned tc = hy0 ^ hz1, td = hy1 ^ hz1;
    const unsigned h0a = (gx ^ ta) & 0x7FFFFu, h1a = (cx1 ^ ta) & 0x7FFFFu;
    const unsigned h0b = (gx ^ tb) & 0x7FFFFu, h1b = (cx1 ^ tb) & 0x7FFFFu;
    const unsigned h0c = (gx ^ tc) & 0x7FFFFu, h1c = (cx1 ^ tc) & 0x7FFFFu;
    const unsigned h0d = (gx ^ td) & 0x7FFFFu, h1d = (cx1 ^ td) & 0x7FFFFu;

    const __half2* tbl = tab + offw;

    // batch A: 4 unconditional aligned 8B pair loads (sc0)
    const unsigned long long da = ld_agent_u64(tbl + (h0a & ~1u));
    const unsigned long long db = ld_agent_u64(tbl + (h0b & ~1u));
    const unsigned long long dc = ld_agent_u64(tbl + (h0c & ~1u));
    const unsigned long long dd = ld_agent_u64(tbl + (h0d & ~1u));
    const unsigned pa_x = (unsigned)da, pa_y = (unsigned)(da >> 32);
    const unsigned pb_x = (unsigned)db, pb_y = (unsigned)(db >> 32);
    const unsigned pc_x = (unsigned)dc, pc_y = (unsigned)(dc >> 32);
    const unsigned pd_x = (unsigned)dd, pd_y = (unsigned)(dd >> 32);

    // batch B: predicated 4B loads for x1 corners outside the pair (sc0)
    unsigned ea, eb, ec, ed;
    if ((h1a >> 1) == (h0a >> 1)) ea = (h1a & 1u) ? pa_y : pa_x;
    else                          ea = ld_agent_u32(tbl + h1a);
    if ((h1b >> 1) == (h0b >> 1)) eb = (h1b & 1u) ? pb_y : pb_x;
    else                          eb = ld_agent_u32(tbl + h1b);
    if ((h1c >> 1) == (h0c >> 1)) ec = (h1c & 1u) ? pc_y : pc_x;
    else                          ec = ld_agent_u32(tbl + h1c);
    if ((h1d >> 1) == (h0d >> 1)) ed = (h1d & 1u) ? pd_y : pd_x;
    else                          ed = ld_agent_u32(tbl + h1d);

    const float wx0 = 1.0f - tx, wx1 = tx;
    const float wy0 = 1.0f - ty, wy1 = ty;
    const float wz0 = 1.0f - tz, wz1 = tz;
    const float wa = wy0 * wz0, wb = wy1 * wz0, wc = wy0 * wz1, wd = wy1 * wz1;

    float a0 = 0.0f, a1 = 0.0f;
    {
        const float2 e0 = h2u_to_f2((h0a & 1u) ? pa_y : pa_x);
        const float2 e1 = h2u_to_f2(ea);
        a0 = fmaf(wa * wx0, e0.x, fmaf(wa * wx1, e1.x, a0));
        a1 = fmaf(wa * wx0, e0.y, fmaf(wa * wx1, e1.y, a1));
    }
    {
        const float2 e0 = h2u_to_f2((h0b & 1u) ? pb_y : pb_x);
        const float2 e1 = h2u_to_f2(eb);
        a0 = fmaf(wb * wx0, e0.x, fmaf(wb * wx1, e1.x, a0));
        a1 = fmaf(wb * wx0, e0.y, fmaf(wb * wx1, e1.y, a1));
    }
    {
        const float2 e0 = h2u_to_f2((h0c & 1u) ? pc_y : pc_x);
        const float2 e1 = h2u_to_f2(ec);
        a0 = fmaf(wc * wx0, e0.x, fmaf(wc * wx1, e1.x, a0));
        a1 = fmaf(wc * wx0, e0.y, fmaf(wc * wx1, e1.y, a1));
    }
    {
        const float2 e0 = h2u_to_f2((h0d & 1u) ? pd_y : pd_x);
        const float2 e1 = h2u_to_f2(ed);
        a0 = fmaf(wd * wx0, e0.x, fmaf(wd * wx1, e1.x, a0));
        a1 = fmaf(wd * wx0, e0.y, fmaf(wd * wx1, e1.y, a1));
    }

    ws[(size_t)cfg.ws_row[l] * npts + p] = __floats2half2_rn(a0, a1);
}

// ---- finalize: dense levels computed inline (tables L1/L2-resident from
// every XCD, 2.3MB total) + hashed rows read from ws; full 128B out row per
// thread. Removing dense levels from the scattered gather cut its work 31%.
__global__ __launch_bounds__(TPB) void finalize_kernel(
    const float* __restrict__ in, const __half2* __restrict__ tab,
    const __half2* __restrict__ ws, float4* __restrict__ out,
    Cfg cfg, int npts)
{
    int p = blockIdx.x * TPB + threadIdx.x;
    if (p >= npts) return;

    const float x = in[3 * p + 0];
    const float y = in[3 * p + 1];
    const float z = in[3 * p + 2];

    float2 fv[NLEVELS];   // fully unrolled static indexing -> registers
    #pragma unroll
    for (int l = 0; l < NLEVELS; ++l) {
        const int row = cfg.ws_row[l];
        if (row >= 0) {
            fv[l] = __half22float2(ws[(size_t)row * npts + p]);
        } else {
            const float    s   = cfg.scale[l];
            const unsigned rr  = cfg.res[l];
            const unsigned off = cfg.offset[l];
            const float px = x * s + 0.5f;
            const float py = y * s + 0.5f;
            const float pz = z * s + 0.5f;
            const float fxf = floorf(px), fyf = floorf(py), fzf = floorf(pz);
            const float tx = px - fxf, ty = py - fyf, tz = pz - fzf;
            const unsigned gx = (unsigned)fxf, gy = (unsigned)fyf, gz = (unsigned)fzf;
            const unsigned rm1 = rr - 1u;
            const unsigned r2 = rr * rr;
            float a0 = 0.0f, a1 = 0.0f;
            #pragma unroll
            for (int c = 0; c < 8; ++c) {
                const unsigned bx = c & 1u, by = (c >> 1) & 1u, bz = (c >> 2) & 1u;
                const unsigned cx = min(gx + bx, rm1);
                const unsigned cy = min(gy + by, rm1);
                const unsigned cz = min(gz + bz, rm1);
                const float w = (bx ? tx : 1.0f - tx)
                              * (by ? ty : 1.0f - ty)
                              * (bz ? tz : 1.0f - tz);
                const unsigned idx = cx + cy * rr + cz * r2;
                const float2 e = __half22float2(tab[off + idx]);
                a0 = fmaf(w, e.x, a0);
                a1 = fmaf(w, e.y, a1);
            }
            fv[l] = make_float2(a0, a1);
        }
    }

    float4* o = out + (size_t)p * 8;
    #pragma unroll
    for (int i = 0; i < 8; ++i)
        o[i] = make_float4(fv[2*i].x, fv[2*i].y, fv[2*i+1].x, fv[2*i+1].y);
}

// ---- monolithic f32 fallback if ws is too small ----
__global__ __launch_bounds__(TPB) void hashenc_mono_kernel(
    const float* __restrict__ in, const float* __restrict__ emb,
    float* __restrict__ out, Cfg cfg, unsigned hash_mask, int npts)
{
    int b = blockIdx.x * TPB + threadIdx.x;
    if (b >= npts) return;
    const float x = in[3*b], y = in[3*b+1], z = in[3*b+2];
    float2* o = reinterpret_cast<float2*>(out) + (size_t)NLEVELS * b;
    #pragma unroll 1
    for (int l = 0; l < NLEVELS; ++l) {
        const float s = cfg.scale[l];
        const unsigned r = cfg.res[l], off = cfg.offset[l];
        const bool use_hash = (hash_mask >> l) & 1u;
        const float px = x*s+0.5f, py = y*s+0.5f, pz = z*s+0.5f;
        const float fxf = floorf(px), fyf = floorf(py), fzf = floorf(pz);
        const float tx = px-fxf, ty = py-fyf, tz = pz-fzf;
        const unsigned gx = (unsigned)fxf, gy = (unsigned)fyf, gz = (unsigned)fzf;
        const unsigned rm1 = r - 1u;
        float a0 = 0.f, a1 = 0.f;
        #pragma unroll
        for (int c = 0; c < 8; ++c) {
            const unsigned bx = c&1u, by = (c>>1)&1u, bz = (c>>2)&1u;
            const unsigned cx = min(gx+bx, rm1), cy = min(gy+by, rm1), cz = min(gz+bz, rm1);
            const float w = (bx?tx:1.f-tx)*(by?ty:1.f-ty)*(bz?tz:1.f-tz);
            unsigned idx = use_hash ? ((cx ^ (cy*2654435761u) ^ (cz*805459861u)) & 0x7FFFFu)
                                    : (cx + cy*r + cz*r*r);
            const float2 e = *reinterpret_cast<const float2*>(emb + 2u*(off+idx));
            a0 = fmaf(w, e.x, a0); a1 = fmaf(w, e.y, a1);
        }
        o[l] = make_float2(a0, a1);
    }
}

extern "C" void kernel_launch(void* const* d_in, const int* in_sizes, int n_in,
                              void* d_out, int out_size, void* d_ws, size_t ws_size,
                              hipStream_t stream)
{
    const float* in  = (const float*)d_in[0];
    const float* emb = (const float*)d_in[1];
    float* out = (float*)d_out;
    const int npts = in_sizes[0] / 3;

    // Build level config exactly like the numpy reference (float64 math).
    Cfg cfg;
    const double pls_log2 = log2(2048.0 / 16.0) / 15.0;
    const long long max_params = 1ll << 19;
    long long off = 0;
    unsigned hash_mask = 0;
    for (int l = 0; l < NLEVELS; ++l) {
        const double scale = exp2((double)l * pls_log2) * 16.0 - 1.0;
        const int res = (int)ceil(scale) + 1;
        cfg.scale[l]  = (float)scale;
        cfg.res[l]    = (unsigned)res;
        cfg.offset[l] = (unsigned)off;
        long long params = (long long)res * res * res;
        if (params > max_params) { params = max_params; hash_mask |= (1u << l); }
        params = (params + 7) / 8 * 8;
        off += params;
    }
    const long long total_entries = off;  // 6098120

    // ws_row: hashed levels get staging rows 0..NH-1; dense -> -1
    int NH = 0;
    for (int l = 0; l < NLEVELS; ++l)
        cfg.ws_row[l] = ((hash_mask >> l) & 1u) ? NH++ : -1;

    const int chunks = (npts + TPB - 1) / TPB;

    // ---- per-XCD balanced run schedule over hashed levels only ----
    int maxq = 0;
    {
        int hashed_lv[NLEVELS];
        int nh = 0;
        for (int l = 0; l < NLEVELS; ++l)
            if ((hash_mask >> l) & 1u) hashed_lv[nh++] = l;
        for (int x = 0; x < NXCD; ++x) {
            for (int r = 0; r < MAXRUNS; ++r) {
                cfg.run_level[x][r] = 0;
                cfg.run_chunk0[x][r] = 0;
                cfg.run_end[x][r] = 0x7fffffff;
            }
            cfg.n_tasks[x] = 0;
        }
        const long long hq_total = (long long)nh * chunks;
        int hi = 0, hc = 0;                               // stream pointers
        for (int x = 0; x < NXCD; ++x) {
            long long hq = hq_total / NXCD + (x < (int)(hq_total % NXCD) ? 1 : 0);
            if ((long long)maxq < hq) maxq = (int)hq;
            int nr = 0;
            long long acc = 0;
            while (hq > 0 && hi < nh) {
                long long rem = (long long)chunks - hc;
                int take = (int)(rem < hq ? rem : hq);
                cfg.run_level [x][nr] = hashed_lv[hi];
                cfg.run_chunk0[x][nr] = hc;
                acc += take;
                cfg.run_end[x][nr] = (int)acc;
                hc += take; if (hc == chunks) { ++hi; hc = 0; }
                hq -= take; ++nr;
            }
            cfg.n_tasks[x] = (int)acc;
        }
    }

    const size_t tab_bytes  = (size_t)total_entries * 4;           // half2/entry
    const size_t tab_pad    = (tab_bytes + 255) & ~(size_t)255;
    const size_t tr_bytes   = (size_t)NH * npts * 4;               // half2 staging

    if (ws_size >= tab_pad + tr_bytes && NH > 0) {
        __half2* tab = (__half2*)d_ws;
        __half2* wst = (__half2*)((char*)d_ws + tab_pad);
        convert_kernel<<<(int)((total_entries + TPB - 1) / TPB), TPB, 0, stream>>>(
            (const float2*)emb, tab, (int)total_entries);
        gather_kernel<<<NXCD * maxq, TPB, 0, stream>>>(in, tab, wst, cfg, npts);
        finalize_kernel<<<chunks, TPB, 0, stream>>>(in, tab, wst, (float4*)out, cfg, npts);
    } else {
        hashenc_mono_kernel<<<chunks, TPB, 0, stream>>>(in, emb, out, cfg, hash_mask, npts);
    }
}